// Round 1
// baseline (409.428 us; speedup 1.0000x reference)
//
#include <hip/hip_runtime.h>
#include <float.h>

// Problem constants (B=16, T=2048, D=256, K=1024)
constexpr int kD = 256;
constexpr int kK = 1024;
constexpr int kN = 16 * 2048;   // 32768 rows
constexpr int MR = 64;          // rows per block
constexpr int KC = 64;          // codes per chunk

// ---------------------------------------------------------------------------
// Kernel A: csqr[k] = ||E[k]||^2. One wave per code row.
__global__ void vq_csqr_kernel(const float* __restrict__ E, float* __restrict__ csqr) {
    const int k = blockIdx.x * 4 + (threadIdx.x >> 6);
    const int lane = threadIdx.x & 63;
    const float4 v = reinterpret_cast<const float4*>(E + (size_t)k * kD)[lane];
    float s = v.x * v.x + v.y * v.y + v.z * v.z + v.w * v.w;
    #pragma unroll
    for (int off = 32; off > 0; off >>= 1) s += __shfl_down(s, off);
    if (lane == 0) csqr[k] = s;
}

// ---------------------------------------------------------------------------
// Kernel B: fused distance GEMM + argmin.
// Block: 256 threads, 64 rows x all 1024 codes (chunks of 64).
// Thread (gr,gc) owns rows gr*4..+3, codes gc*4..+3 within each chunk.
// dist(r,c) = csqr[c] - 2 * dot(x_r, e_c)   (||x||^2 dropped: argmin-invariant)
__global__ __launch_bounds__(256, 1) void vq_argmin_kernel(
    const float* __restrict__ X, const float* __restrict__ E,
    const float* __restrict__ csqr, int* __restrict__ idx_out,
    float* __restrict__ idxf_out)
{
    __shared__ float As[kD][MR];        // transposed X tile: As[d][r]  (64 KB)
    __shared__ float Bs[kD][KC];        // transposed E tile: Bs[d][c]  (64 KB)
    __shared__ float red_val[MR][16];
    __shared__ int   red_idx[MR][16];

    const int t = threadIdx.x;
    const int gr = t >> 4;              // 0..15 row group
    const int gc = t & 15;              // 0..15 code group
    const int row_base = blockIdx.x * MR;

    // Stage X tile transposed. Lane-contiguous ds_writes (conflict-free);
    // 1KB-strided global float4 reads whose 64B lines are fully consumed
    // across the 4 waves (clean 32 MB total fetch).
    {
        const int r = t & 63;
        const int d4b = t >> 6;         // 0..3
        const float4* Xr = reinterpret_cast<const float4*>(X + (size_t)(row_base + r) * kD);
        #pragma unroll
        for (int it = 0; it < 16; ++it) {
            const int d4 = d4b + it * 4;          // 0..63
            const float4 v = Xr[d4];
            As[d4 * 4 + 0][r] = v.x;
            As[d4 * 4 + 1][r] = v.y;
            As[d4 * 4 + 2][r] = v.z;
            As[d4 * 4 + 3][r] = v.w;
        }
    }

    float best_val[4];
    int   best_idx[4];
    #pragma unroll
    for (int i = 0; i < 4; ++i) { best_val[i] = FLT_MAX; best_idx[i] = 0; }

    for (int chunk = 0; chunk < kK / KC; ++chunk) {
        __syncthreads();                 // previous compute done before restaging Bs
        {
            const int c = t & 63;
            const int d4b = t >> 6;
            const float4* Er = reinterpret_cast<const float4*>(
                E + (size_t)(chunk * KC + c) * kD);
            #pragma unroll
            for (int it = 0; it < 16; ++it) {
                const int d4 = d4b + it * 4;
                const float4 v = Er[d4];
                Bs[d4 * 4 + 0][c] = v.x;
                Bs[d4 * 4 + 1][c] = v.y;
                Bs[d4 * 4 + 2][c] = v.z;
                Bs[d4 * 4 + 3][c] = v.w;
            }
        }
        __syncthreads();

        float acc[4][4];
        #pragma unroll
        for (int i = 0; i < 4; ++i)
            #pragma unroll
            for (int j = 0; j < 4; ++j) acc[i][j] = 0.0f;

        #pragma unroll 8
        for (int d = 0; d < kD; ++d) {
            const float4 a = *reinterpret_cast<const float4*>(&As[d][gr * 4]);
            const float4 b = *reinterpret_cast<const float4*>(&Bs[d][gc * 4]);
            const float av[4] = {a.x, a.y, a.z, a.w};
            const float bv[4] = {b.x, b.y, b.z, b.w};
            #pragma unroll
            for (int i = 0; i < 4; ++i)
                #pragma unroll
                for (int j = 0; j < 4; ++j)
                    acc[i][j] = fmaf(av[i], bv[j], acc[i][j]);
        }

        const int cbase = chunk * KC + gc * 4;
        float cs[4];
        #pragma unroll
        for (int j = 0; j < 4; ++j) cs[j] = csqr[cbase + j];
        #pragma unroll
        for (int i = 0; i < 4; ++i) {
            #pragma unroll
            for (int j = 0; j < 4; ++j) {
                const float dist = fmaf(-2.0f, acc[i][j], cs[j]);
                if (dist < best_val[i]) { best_val[i] = dist; best_idx[i] = cbase + j; }
            }
        }
    }

    // Cross-group reduction: 16 gc-threads per row -> one (val,idx)
    #pragma unroll
    for (int i = 0; i < 4; ++i) {
        red_val[gr * 4 + i][gc] = best_val[i];
        red_idx[gr * 4 + i][gc] = best_idx[i];
    }
    __syncthreads();
    if (t < MR) {
        float bv = red_val[t][0];
        int   bi = red_idx[t][0];
        #pragma unroll
        for (int g = 1; g < 16; ++g) {
            const float v = red_val[t][g];
            const int   i = red_idx[t][g];
            // lower value wins; on exact tie, lower code index wins (matches argmin-first)
            if (v < bv || (v == bv && i < bi)) { bv = v; bi = i; }
        }
        idx_out[row_base + t] = bi;
        idxf_out[row_base + t] = (float)bi;
    }
}

// ---------------------------------------------------------------------------
// Kernel C: gather codes -> z_q_x and z_q_x_bar (identical in eval mode).
__global__ void vq_gather_kernel(const float* __restrict__ E, const int* __restrict__ idx,
                                 float* __restrict__ zq, float* __restrict__ zqb) {
    const int row = blockIdx.x * 4 + (threadIdx.x >> 6);
    const int lane = threadIdx.x & 63;
    const int k = idx[row];
    const float4 v = reinterpret_cast<const float4*>(E + (size_t)k * kD)[lane];
    reinterpret_cast<float4*>(zq + (size_t)row * kD)[lane] = v;
    reinterpret_cast<float4*>(zqb + (size_t)row * kD)[lane] = v;
}

// ---------------------------------------------------------------------------
extern "C" void kernel_launch(void* const* d_in, const int* in_sizes, int n_in,
                              void* d_out, int out_size, void* d_ws, size_t ws_size,
                              hipStream_t stream) {
    const float* X = (const float*)d_in[0];      // z_e_x  [N, D]
    const float* E = (const float*)d_in[1];      // embedding [K, D]

    float* out  = (float*)d_out;
    float* zq   = out;                               // [N*D]
    float* zqb  = out + (size_t)kN * kD;             // [N*D]
    float* idxf = out + 2 * (size_t)kN * kD;         // [N]

    float* csqr = (float*)d_ws;                                  // K floats
    int*   idx  = (int*)((char*)d_ws + kK * sizeof(float));      // N ints

    vq_csqr_kernel<<<kK / 4, 256, 0, stream>>>(E, csqr);
    vq_argmin_kernel<<<kN / MR, 256, 0, stream>>>(X, E, csqr, idx, idxf);
    vq_gather_kernel<<<kN / 4, 256, 0, stream>>>(E, idx, zq, zqb);
}

// Round 2
// 315.661 us; speedup vs baseline: 1.2971x; 1.2971x over previous
//
#include <hip/hip_runtime.h>
#include <float.h>

// Problem constants (B=16, T=2048, D=256, K=1024)
constexpr int kD = 256;
constexpr int kK = 1024;
constexpr int kN = 16 * 2048;     // 32768 rows
constexpr int MR = 128;           // rows per block tile
constexpr int KC = 128;           // codes per chunk
constexpr int DC = 32;            // d-slice per staging round
constexpr int NSPLIT = 4;         // codebook splits (occupancy)
constexpr int KSPLIT = kK / NSPLIT;

// ---------------------------------------------------------------------------
// Kernel A: csqr[k] = ||E[k]||^2. One wave per code row.
__global__ void vq_csqr_kernel(const float* __restrict__ E, float* __restrict__ csqr) {
    const int k = blockIdx.x * 4 + (threadIdx.x >> 6);
    const int lane = threadIdx.x & 63;
    const float4 v = reinterpret_cast<const float4*>(E + (size_t)k * kD)[lane];
    float s = v.x * v.x + v.y * v.y + v.z * v.z + v.w * v.w;
    #pragma unroll
    for (int off = 32; off > 0; off >>= 1) s += __shfl_down(s, off);
    if (lane == 0) csqr[k] = s;
}

// ---------------------------------------------------------------------------
// Kernel B: fused distance GEMM + per-split argmin.
// Block tile: 128 rows x 256 codes (one split), chunks of 128 codes, d in
// slices of 32. Thread (gr,gc) owns rows {gr*4..+3, 64+gr*4..+3} and codes
// {gc*4..+3, 64+gc*4..+3} -> 8x8 micro-tile = 64 FMA per 4 ds_read_b128.
// The 64+ split keeps every LDS read at lane-stride 16B (<=2-way conflict).
// dist(r,c) = csqr[c] - 2*dot(x_r,e_c)  (||x||^2 dropped: argmin-invariant)
__global__ __launch_bounds__(256, 3) void vq_argmin_kernel(
    const float* __restrict__ X, const float* __restrict__ E,
    const float* __restrict__ csqr,
    float* __restrict__ cand_val, int* __restrict__ cand_idx)
{
    __shared__ __align__(16) union SM {
        struct { float As[DC][MR]; float Bs[DC][KC]; } s;   // 32 KB
        struct { float val[MR][16]; int idx[MR][16]; } r;   // 16 KB (reuse)
    } sm;

    const int t = threadIdx.x;
    const int gr = t >> 4;          // 0..15 row group
    const int gc = t & 15;          // 0..15 code group
    const int row_base = blockIdx.x * MR;
    const int code_base = blockIdx.y * KSPLIT;

    const int sr = t >> 1;          // staging row 0..127
    const int shalf = t & 1;        // staging half (16 floats each)

    float best_val[8];
    int   best_idx[8];
    #pragma unroll
    for (int i = 0; i < 8; ++i) { best_val[i] = FLT_MAX; best_idx[i] = 0; }

    for (int chunk = 0; chunk < KSPLIT / KC; ++chunk) {
        float acc[8][8];
        #pragma unroll
        for (int i = 0; i < 8; ++i)
            #pragma unroll
            for (int j = 0; j < 8; ++j) acc[i][j] = 0.0f;

        for (int dc = 0; dc < kD / DC; ++dc) {
            __syncthreads();          // previous slice's reads done
            {
                const float4* Xr = reinterpret_cast<const float4*>(
                    X + (size_t)(row_base + sr) * kD + dc * DC) + shalf * 4;
                const float4* Er = reinterpret_cast<const float4*>(
                    E + (size_t)(code_base + chunk * KC + sr) * kD + dc * DC) + shalf * 4;
                #pragma unroll
                for (int i = 0; i < 4; ++i) {
                    const float4 v = Xr[i];
                    const float4 w = Er[i];
                    const int d0 = (shalf * 4 + i) * 4;
                    sm.s.As[d0 + 0][sr] = v.x; sm.s.As[d0 + 1][sr] = v.y;
                    sm.s.As[d0 + 2][sr] = v.z; sm.s.As[d0 + 3][sr] = v.w;
                    sm.s.Bs[d0 + 0][sr] = w.x; sm.s.Bs[d0 + 1][sr] = w.y;
                    sm.s.Bs[d0 + 2][sr] = w.z; sm.s.Bs[d0 + 3][sr] = w.w;
                }
            }
            __syncthreads();

            #pragma unroll 4
            for (int d = 0; d < DC; ++d) {
                const float4 a0 = *reinterpret_cast<const float4*>(&sm.s.As[d][gr * 4]);
                const float4 a1 = *reinterpret_cast<const float4*>(&sm.s.As[d][64 + gr * 4]);
                const float4 b0 = *reinterpret_cast<const float4*>(&sm.s.Bs[d][gc * 4]);
                const float4 b1 = *reinterpret_cast<const float4*>(&sm.s.Bs[d][64 + gc * 4]);
                const float av[8] = {a0.x, a0.y, a0.z, a0.w, a1.x, a1.y, a1.z, a1.w};
                const float bv[8] = {b0.x, b0.y, b0.z, b0.w, b1.x, b1.y, b1.z, b1.w};
                #pragma unroll
                for (int i = 0; i < 8; ++i)
                    #pragma unroll
                    for (int j = 0; j < 8; ++j)
                        acc[i][j] = fmaf(av[i], bv[j], acc[i][j]);
            }
        }

        // distances + local argmin. Codes visited in ascending index order
        // (j 0..3 low half, 4..7 at +64) with strict '<' => first-occurrence.
        const int cb = code_base + chunk * KC;
        int cidx[8]; float cs[8];
        #pragma unroll
        for (int j = 0; j < 4; ++j) {
            cidx[j]     = cb + gc * 4 + j;
            cidx[4 + j] = cb + 64 + gc * 4 + j;
        }
        #pragma unroll
        for (int j = 0; j < 8; ++j) cs[j] = csqr[cidx[j]];
        #pragma unroll
        for (int i = 0; i < 8; ++i) {
            #pragma unroll
            for (int j = 0; j < 8; ++j) {
                const float dist = fmaf(-2.0f, acc[i][j], cs[j]);
                if (dist < best_val[i]) { best_val[i] = dist; best_idx[i] = cidx[j]; }
            }
        }
    }

    // Cross-thread reduction over the 16 gc groups, reusing the tile LDS.
    __syncthreads();
    #pragma unroll
    for (int i = 0; i < 8; ++i) {
        const int lr = (i < 4) ? (gr * 4 + i) : (64 + gr * 4 + (i - 4));
        sm.r.val[lr][gc] = best_val[i];
        sm.r.idx[lr][gc] = best_idx[i];
    }
    __syncthreads();
    if (t < MR) {
        float bv = sm.r.val[t][0];
        int   bi = sm.r.idx[t][0];
        #pragma unroll
        for (int g = 1; g < 16; ++g) {
            const float v = sm.r.val[t][g];
            const int  i2 = sm.r.idx[t][g];
            if (v < bv || (v == bv && i2 < bi)) { bv = v; bi = i2; }
        }
        cand_val[(size_t)blockIdx.y * kN + row_base + t] = bv;
        cand_idx[(size_t)blockIdx.y * kN + row_base + t] = bi;
    }
}

// ---------------------------------------------------------------------------
// Kernel C: combine the NSPLIT per-split candidates per row.
__global__ void vq_combine_kernel(const float* __restrict__ cand_val,
                                  const int* __restrict__ cand_idx,
                                  int* __restrict__ idx, float* __restrict__ idxf)
{
    const int row = blockIdx.x * 256 + threadIdx.x;
    float bv = cand_val[row];
    int   bi = cand_idx[row];
    #pragma unroll
    for (int s = 1; s < NSPLIT; ++s) {
        const float v = cand_val[(size_t)s * kN + row];
        const int  i2 = cand_idx[(size_t)s * kN + row];
        if (v < bv || (v == bv && i2 < bi)) { bv = v; bi = i2; }
    }
    idx[row]  = bi;
    idxf[row] = (float)bi;
}

// ---------------------------------------------------------------------------
// Kernel D: gather codes -> z_q_x and z_q_x_bar (identical in eval mode).
__global__ void vq_gather_kernel(const float* __restrict__ E, const int* __restrict__ idx,
                                 float* __restrict__ zq, float* __restrict__ zqb) {
    const int row = blockIdx.x * 4 + (threadIdx.x >> 6);
    const int lane = threadIdx.x & 63;
    const int k = idx[row];
    const float4 v = reinterpret_cast<const float4*>(E + (size_t)k * kD)[lane];
    reinterpret_cast<float4*>(zq + (size_t)row * kD)[lane] = v;
    reinterpret_cast<float4*>(zqb + (size_t)row * kD)[lane] = v;
}

// ---------------------------------------------------------------------------
extern "C" void kernel_launch(void* const* d_in, const int* in_sizes, int n_in,
                              void* d_out, int out_size, void* d_ws, size_t ws_size,
                              hipStream_t stream) {
    const float* X = (const float*)d_in[0];      // z_e_x  [N, D]
    const float* E = (const float*)d_in[1];      // embedding [K, D]

    float* out  = (float*)d_out;
    float* zq   = out;                               // [N*D]
    float* zqb  = out + (size_t)kN * kD;             // [N*D]
    float* idxf = out + 2 * (size_t)kN * kD;         // [N]

    // workspace layout
    char* ws = (char*)d_ws;
    float* csqr     = (float*)ws;                               ws += kK * sizeof(float);
    float* cand_val = (float*)ws;                               ws += (size_t)NSPLIT * kN * sizeof(float);
    int*   cand_idx = (int*)ws;                                 ws += (size_t)NSPLIT * kN * sizeof(int);
    int*   idx      = (int*)ws;

    vq_csqr_kernel<<<kK / 4, 256, 0, stream>>>(E, csqr);
    vq_argmin_kernel<<<dim3(kN / MR, NSPLIT), 256, 0, stream>>>(X, E, csqr, cand_val, cand_idx);
    vq_combine_kernel<<<kN / 256, 256, 0, stream>>>(cand_val, cand_idx, idx, idxf);
    vq_gather_kernel<<<kN / 4, 256, 0, stream>>>(E, idx, zq, zqb);
}

// Round 3
// 243.611 us; speedup vs baseline: 1.6807x; 1.2958x over previous
//
#include <hip/hip_runtime.h>
#include <float.h>

// Problem constants (B=16, T=2048, D=256, K=1024)
constexpr int kD = 256;
constexpr int kK = 1024;
constexpr int kN = 16 * 2048;   // 32768 rows

using bf16x8 = __attribute__((ext_vector_type(8))) short;
using f32x16 = __attribute__((ext_vector_type(16))) float;
using u16x8  = __attribute__((ext_vector_type(8))) unsigned short;

__device__ __forceinline__ unsigned short f2bf(float x) {
    union { float f; unsigned u; } a; a.f = x;
    const unsigned u = a.u;
    return (unsigned short)((u + 0x7fffu + ((u >> 16) & 1u)) >> 16);   // RNE
}
__device__ __forceinline__ float bf2f(unsigned short b) {
    union { unsigned u; float f; } a; a.u = ((unsigned)b) << 16;
    return a.f;
}

#define GLOAD_LDS16(GP, LP) \
    __builtin_amdgcn_global_load_lds((const __attribute__((address_space(1))) unsigned int*)(GP), \
                                     (__attribute__((address_space(3))) unsigned int*)(LP), 16, 0, 0)

// ---------------------------------------------------------------------------
// Kernel P: split fp32 rows into (h,m,l) bf16 triples, written in MFMA
// fragment-image order. For 64-row block RB, unit u in [0,2048):
//   l=u&63, f=(u>>6)&1, t16=u>>7
//   data  = split(src[RB*64 + f*32 + (l&31)][t16*16 + (l>>5)*8 .. +7])
//   dest  = out + RB*32KB + u*16B      (so GEMM staging & ds_reads are linear)
__global__ void vq_split_kernel(const float* __restrict__ src,
                                unsigned short* __restrict__ oh,
                                unsigned short* __restrict__ om,
                                unsigned short* __restrict__ ol) {
    const int RB = blockIdx.x;
    const int t  = threadIdx.x;
    #pragma unroll
    for (int it = 0; it < 8; ++it) {
        const int u   = it * 256 + t;
        const int l   = u & 63;
        const int f   = (u >> 6) & 1;
        const int t16 = u >> 7;
        const int row = RB * 64 + f * 32 + (l & 31);
        const int d0  = t16 * 16 + (l >> 5) * 8;
        const float4 v0 = *reinterpret_cast<const float4*>(src + (size_t)row * kD + d0);
        const float4 v1 = *reinterpret_cast<const float4*>(src + (size_t)row * kD + d0 + 4);
        const float x[8] = {v0.x, v0.y, v0.z, v0.w, v1.x, v1.y, v1.z, v1.w};
        u16x8 H, M, L;
        #pragma unroll
        for (int e = 0; e < 8; ++e) {
            const unsigned short h = f2bf(x[e]);
            const float r1 = x[e] - bf2f(h);          // Sterbenz-exact
            const unsigned short m = f2bf(r1);
            const float r2 = r1 - bf2f(m);            // exact
            const unsigned short lo = f2bf(r2);
            H[e] = (short)h; M[e] = (short)m; L[e] = (short)lo;
        }
        const size_t o = (size_t)RB * 16384 + (size_t)u * 8;
        *reinterpret_cast<u16x8*>(oh + o) = H;
        *reinterpret_cast<u16x8*>(om + o) = M;
        *reinterpret_cast<u16x8*>(ol + o) = L;
    }
}

// ---------------------------------------------------------------------------
// Kernel A: csqr[k] = ||E[k]||^2 (fp32, matches reference codebook_sqr).
__global__ void vq_csqr_kernel(const float* __restrict__ E, float* __restrict__ csqr) {
    const int k = blockIdx.x * 4 + (threadIdx.x >> 6);
    const int lane = threadIdx.x & 63;
    const float4 v = reinterpret_cast<const float4*>(E + (size_t)k * kD)[lane];
    float s = v.x * v.x + v.y * v.y + v.z * v.z + v.w * v.w;
    #pragma unroll
    for (int off = 32; off > 0; off >>= 1) s += __shfl_down(s, off);
    if (lane == 0) csqr[k] = s;
}

// ---------------------------------------------------------------------------
// Kernel G: MFMA distance GEMM (6-pass bf16x3 split == fp32-exact) + argmin.
// Block 128 rows x 128 codes, 4 waves 2x2, wave tile 64x64 (2x2 MFMAs of
// 32x32x16). DC=32 per chunk: 48 segs of 1KB staged via global_load_lds(16).
// dist(r,c) = csqr[c] - 2*dot  (||x||^2 dropped: argmin-invariant per row).
__global__ __launch_bounds__(256, 3) void vq_gemm_kernel(
    const unsigned short* __restrict__ xh, const unsigned short* __restrict__ xm,
    const unsigned short* __restrict__ xl,
    const unsigned short* __restrict__ eh, const unsigned short* __restrict__ em,
    const unsigned short* __restrict__ el,
    const float* __restrict__ csqr,
    float* __restrict__ cand_val, int* __restrict__ cand_idx)
{
    __shared__ bf16x8 smem[3072];          // 48 KB: A = [0,1536), B = [1536,3072) units
    const int tid  = threadIdx.x;
    const int lane = tid & 63;
    const int wid  = tid >> 6;
    const int wr   = wid >> 1;             // wave row-group (rows wr*64..+63)
    const int wc   = wid & 1;              // wave col-group (cols wc*64..+63)

    // XCD-bijective decode: all 8 code-blocks of a row-panel land on one XCD
    // -> X-panel slice (3MB) + E image (1.5MB) L2-resident per XCD.
    const int w    = blockIdx.x;
    const int xcd  = w & 7;
    const int slot = w >> 3;
    const int rb   = xcd * 32 + (slot >> 3);   // 0..255 row-block (128 rows)
    const int cb   = slot & 7;                 // 0..7  code-block (128 codes)

    f32x16 acc00 = {}, acc01 = {}, acc10 = {}, acc11 = {};

    for (int c = 0; c < 8; ++c) {              // 8 chunks of DC=32 over D=256
        __syncthreads();                       // prev chunk's ds_reads done
        #pragma unroll
        for (int k2 = 0; k2 < 12; ++k2) {      // 48 segs / 4 waves
            const int sg  = wid + k2 * 4;
            const bool isB = sg >= 24;
            const int q  = isB ? sg - 24 : sg;
            const int f  = q & 1, tt = (q >> 1) & 1, g = (q >> 2) & 1, s = q >> 3;
            const unsigned short* base = isB ? (s == 0 ? eh : s == 1 ? em : el)
                                             : (s == 0 ? xh : s == 1 ? xm : xl);
            const int RBx = (isB ? cb : rb) * 2 + g;
            const size_t unit = ((size_t)(RBx * 16 + c * 2 + tt) * 2 + f) * 512 + lane * 8;
            GLOAD_LDS16(base + unit, &smem[sg * 64]);
        }
        __syncthreads();                       // implies vmcnt(0) drain

        #pragma unroll
        for (int tt = 0; tt < 2; ++tt) {       // 2 k-steps of 16
            const int ab = wr * 256 + tt * 128 + lane;
            const int bb = 1536 + wc * 256 + tt * 128 + lane;
            const bf16x8 ah0 = smem[ab];            const bf16x8 ah1 = smem[ab + 64];
            const bf16x8 am0 = smem[ab + 512];      const bf16x8 am1 = smem[ab + 576];
            const bf16x8 al0 = smem[ab + 1024];     const bf16x8 al1 = smem[ab + 1088];
            const bf16x8 bh0 = smem[bb];            const bf16x8 bh1 = smem[bb + 64];
            const bf16x8 bm0 = smem[bb + 512];      const bf16x8 bm1 = smem[bb + 576];
            const bf16x8 bl0 = smem[bb + 1024];     const bf16x8 bl1 = smem[bb + 1088];
#define MFMA(A,B,C) __builtin_amdgcn_mfma_f32_32x32x16_bf16(A, B, C, 0, 0, 0)
            acc00 = MFMA(ah0, bh0, acc00); acc01 = MFMA(ah0, bh1, acc01);   // hh
            acc10 = MFMA(ah1, bh0, acc10); acc11 = MFMA(ah1, bh1, acc11);
            acc00 = MFMA(ah0, bm0, acc00); acc01 = MFMA(ah0, bm1, acc01);   // hm
            acc10 = MFMA(ah1, bm0, acc10); acc11 = MFMA(ah1, bm1, acc11);
            acc00 = MFMA(am0, bh0, acc00); acc01 = MFMA(am0, bh1, acc01);   // mh
            acc10 = MFMA(am1, bh0, acc10); acc11 = MFMA(am1, bh1, acc11);
            acc00 = MFMA(ah0, bl0, acc00); acc01 = MFMA(ah0, bl1, acc01);   // hl
            acc10 = MFMA(ah1, bl0, acc10); acc11 = MFMA(ah1, bl1, acc11);
            acc00 = MFMA(al0, bh0, acc00); acc01 = MFMA(al0, bh1, acc01);   // lh
            acc10 = MFMA(al1, bh0, acc10); acc11 = MFMA(al1, bh1, acc11);
            acc00 = MFMA(am0, bm0, acc00); acc01 = MFMA(am0, bm1, acc01);   // mm
            acc10 = MFMA(am1, bm0, acc10); acc11 = MFMA(am1, bm1, acc11);
#undef MFMA
        }
    }

    // Fused argmin epilogue. C/D layout: col = lane&31,
    // row = (reg&3) + 8*(reg>>2) + 4*(lane>>5)  [m74/m101 verified].
    const int colA  = cb * 128 + wc * 64 + (lane & 31);
    const float csA = csqr[colA];
    const float csB = csqr[colA + 32];
    const int rbase = rb * 128 + wr * 64 + 4 * (lane >> 5);
    const int cslot = cb * 2 + wc;

    #pragma unroll
    for (int half = 0; half < 2; ++half) {
        #pragma unroll
        for (int r = 0; r < 16; ++r) {
            const float s0 = (half == 0) ? acc00[r] : acc10[r];
            const float s1 = (half == 0) ? acc01[r] : acc11[r];
            float bv = fmaf(-2.0f, s0, csA);
            int   bi = colA;
            const float v1 = fmaf(-2.0f, s1, csB);
            if (v1 < bv) { bv = v1; bi = colA + 32; }          // colA < colA+32: '<' keeps first
            #pragma unroll
            for (int mk = 16; mk >= 1; mk >>= 1) {             // reduce 32 lanes (per half)
                const float ov = __shfl_xor(bv, mk);
                const int   oi = __shfl_xor(bi, mk);
                if (ov < bv || (ov == bv && oi < bi)) { bv = ov; bi = oi; }
            }
            if ((lane & 31) == 0) {
                const int row = rbase + half * 32 + (r & 3) + 8 * (r >> 2);
                cand_val[(size_t)cslot * kN + row] = bv;
                cand_idx[(size_t)cslot * kN + row] = bi;
            }
        }
    }
}

// ---------------------------------------------------------------------------
// Kernel C: combine 16 per-column-slot candidates per row (ascending slot ==
// ascending code index -> first-occurrence tie semantics).
__global__ void vq_combine_kernel(const float* __restrict__ cand_val,
                                  const int* __restrict__ cand_idx,
                                  int* __restrict__ idx, float* __restrict__ idxf)
{
    const int row = blockIdx.x * 256 + threadIdx.x;
    float bv = cand_val[row];
    int   bi = cand_idx[row];
    #pragma unroll
    for (int s = 1; s < 16; ++s) {
        const float v = cand_val[(size_t)s * kN + row];
        const int  i2 = cand_idx[(size_t)s * kN + row];
        if (v < bv || (v == bv && i2 < bi)) { bv = v; bi = i2; }
    }
    idx[row]  = bi;
    idxf[row] = (float)bi;
}

// ---------------------------------------------------------------------------
// Kernel D: gather codes -> z_q_x and z_q_x_bar (identical in eval mode).
__global__ void vq_gather_kernel(const float* __restrict__ E, const int* __restrict__ idx,
                                 float* __restrict__ zq, float* __restrict__ zqb) {
    const int row = blockIdx.x * 4 + (threadIdx.x >> 6);
    const int lane = threadIdx.x & 63;
    const int k = idx[row];
    const float4 v = reinterpret_cast<const float4*>(E + (size_t)k * kD)[lane];
    reinterpret_cast<float4*>(zq + (size_t)row * kD)[lane] = v;
    reinterpret_cast<float4*>(zqb + (size_t)row * kD)[lane] = v;
}

// ---------------------------------------------------------------------------
extern "C" void kernel_launch(void* const* d_in, const int* in_sizes, int n_in,
                              void* d_out, int out_size, void* d_ws, size_t ws_size,
                              hipStream_t stream) {
    const float* X = (const float*)d_in[0];      // z_e_x  [N, D]
    const float* E = (const float*)d_in[1];      // embedding [K, D]

    float* out  = (float*)d_out;
    float* zq   = out;                           // [N*D]
    float* zqb  = out + (size_t)kN * kD;         // [N*D]
    float* idxf = out + 2 * (size_t)kN * kD;     // [N]

    // Big scratch lives in d_out ([0,52MB)) and is fully overwritten by the
    // final gather ([0,64MB)) + combine (idxf). Stream order serializes.
    char* ob = (char*)d_out;
    unsigned short* XIh = (unsigned short*)ob;                   // 16 MB
    unsigned short* XIm = XIh + (size_t)kN * kD;                 // 16 MB
    unsigned short* XIl = XIm + (size_t)kN * kD;                 // 16 MB
    float* cand_val = (float*)(ob + 3ull * kN * kD * 2);         // 2 MB @48MB
    int*   cand_idx = (int*)(ob + 3ull * kN * kD * 2 + 16ull * kN * 4); // 2 MB

    // Small scratch in ws (~1.7 MB)
    char* ws = (char*)d_ws;
    float* csqr = (float*)ws;
    unsigned short* EIh = (unsigned short*)(ws + 4096);
    unsigned short* EIm = EIh + (size_t)kK * kD;
    unsigned short* EIl = EIm + (size_t)kK * kD;
    int* idx = (int*)(ws + 4096 + 3ull * kK * kD * 2);

    vq_split_kernel<<<kN / 64, 256, 0, stream>>>(X, XIh, XIm, XIl);
    vq_split_kernel<<<kK / 64, 256, 0, stream>>>(E, EIh, EIm, EIl);
    vq_csqr_kernel<<<kK / 4, 256, 0, stream>>>(E, csqr);
    vq_gemm_kernel<<<(kN / 128) * (kK / 128), 256, 0, stream>>>(
        XIh, XIm, XIl, EIh, EIm, EIl, csqr, cand_val, cand_idx);
    vq_combine_kernel<<<kN / 256, 256, 0, stream>>>(cand_val, cand_idx, idx, idxf);
    vq_gather_kernel<<<kN / 4, 256, 0, stream>>>(E, idx, zq, zqb);
}